// Round 1
// 1156.520 us; speedup vs baseline: 1.1046x; 1.1046x over previous
//
#include <hip/hip_runtime.h>
#include <stdint.h>

#define TOKENS 2048
#define H_DIM 3584
#define I_DIM 18944

typedef int v4i __attribute__((ext_vector_type(4)));

__device__ __forceinline__ void async_copy16(const void* g, void* lds) {
    __builtin_amdgcn_global_load_lds(
        (const __attribute__((address_space(1))) void*)g,
        (__attribute__((address_space(3))) void*)lds,
        16, 0, 0);
}

// BK=128 LDS swizzle: rows are 128 B = 8 slots of 16 B. Physical chunk
// (row, s) holds global k-chunk s ^ (row&7). Staging thread t owns rows
// (t>>3)+R*j (R multiple of 8), phys slot t&7, so its pre-swizzled global
// k-offset ((t&7)^((t>>3)&7))*16 is the same for all j. Reader of
// (row, logical chunk L=kh*4+fq) uses slot L^(fr&7) (row&7==fr&7 always):
// 8 lanes per 16B slot -> conflict-free ds_read_b128 (measured 0).

// ---------------------------------------------------------------------------
// Kernel 0: pack all three int32-materialized int8 weights in ONE launch
// ---------------------------------------------------------------------------
__global__ __launch_bounds__(256)
void pack3_kernel(const int* __restrict__ s0, int8_t* __restrict__ d0,
                  const int* __restrict__ s1, int8_t* __restrict__ d1,
                  const int* __restrict__ s2, int8_t* __restrict__ d2,
                  int pb) {
    int b = blockIdx.x;
    const int* src; int8_t* dst;
    if (b >= 2 * pb)    { src = s2; dst = d2; b -= 2 * pb; }
    else if (b >= pb)   { src = s1; dst = d1; b -= pb; }
    else                { src = s0; dst = d0; }
    const int i = b * 256 + threadIdx.x;           // exact: no tail
    v4i w = ((const v4i*)src)[i];
    int packed = (w.x & 0xff) | ((w.y & 0xff) << 8) |
                 ((w.z & 0xff) << 16) | (w.w << 24);
    ((int*)dst)[i] = packed;
}

// ---------------------------------------------------------------------------
// Kernel 1: per-token dynamic symmetric int8 quant of x [T, H], float4 loads
// ---------------------------------------------------------------------------
__global__ __launch_bounds__(256)
void quant_x_kernel(const float* __restrict__ x,
                    int8_t* __restrict__ qx,
                    float* __restrict__ sx) {
    const int row = blockIdx.x;
    const float4* xr = (const float4*)(x + (size_t)row * H_DIM);   // 896 vecs
    float m = 0.0f;
    for (int j = threadIdx.x; j < 896; j += 256) {
        float4 v = xr[j];
        m = fmaxf(m, fmaxf(fmaxf(fabsf(v.x), fabsf(v.y)),
                           fmaxf(fabsf(v.z), fabsf(v.w))));
    }
    for (int off = 32; off > 0; off >>= 1)
        m = fmaxf(m, __shfl_down(m, off, 64));
    __shared__ float wmax[4];
    if ((threadIdx.x & 63) == 0) wmax[threadIdx.x >> 6] = m;
    __syncthreads();
    float mm = fmaxf(fmaxf(wmax[0], wmax[1]), fmaxf(wmax[2], wmax[3]));
    float s = fmaxf(mm / 127.0f, 1e-8f);
    if (threadIdx.x == 0) sx[row] = s;
    int* qrow = (int*)(qx + (size_t)row * H_DIM);
    for (int j = threadIdx.x; j < 896; j += 256) {
        float4 v = xr[j];
        int q0 = (int)fminf(fmaxf(rintf(v.x / s), -127.0f), 127.0f);
        int q1 = (int)fminf(fmaxf(rintf(v.y / s), -127.0f), 127.0f);
        int q2 = (int)fminf(fmaxf(rintf(v.z / s), -127.0f), 127.0f);
        int q3 = (int)fminf(fmaxf(rintf(v.w / s), -127.0f), 127.0f);
        qrow[j] = (q0 & 0xff) | ((q1 & 0xff) << 8) | ((q2 & 0xff) << 16) |
                  (q3 << 24);
    }
}

// ---------------------------------------------------------------------------
// Kernel 2: fused fc1 — gate & up int8 GEMM + SwiGLU + static requant
//   BM=256, BN=128 I-cols (B tile = 128 G rows + 128 U rows), BK=128.
//   512 threads / 8 waves, wave tile 128(M) x 32 I-cols (64 eff N).
//   4-phase schedule per K-tile, double-buffered 128 KiB LDS, prefetch
//   issued phases 0-1, drained at tile-end __syncthreads (distance ~2.5
//   phases). setprio around each 16-MFMA cluster.
// ---------------------------------------------------------------------------
#define FC1_LOADA(MH) do { _Pragma("unroll")                                   \
  for (int m_ = 0; m_ < 4; ++m_) {                                             \
    a[m_][0] = *(const v4i*)(Ab + aOff + (MH)*8192 + m_*2048 + sw0);           \
    a[m_][1] = *(const v4i*)(Ab + aOff + (MH)*8192 + m_*2048 + sw1);           \
  } } while (0)

#define FC1_LOADB(NF) do {                                                     \
    bg[NF][0] = *(const v4i*)(Bb + bOff + (NF)*2048 + sw0);                    \
    bg[NF][1] = *(const v4i*)(Bb + bOff + (NF)*2048 + sw1);                    \
    bu[NF][0] = *(const v4i*)(Bb + 16384 + bOff + (NF)*2048 + sw0);            \
    bu[NF][1] = *(const v4i*)(Bb + 16384 + bOff + (NF)*2048 + sw1);            \
  } while (0)

#define FC1_MFMA(MH, NF) do { _Pragma("unroll")                                \
  for (int m_ = 0; m_ < 4; ++m_) {                                             \
    accG[(MH)*4+m_][NF] = __builtin_amdgcn_mfma_i32_16x16x64_i8(               \
        a[m_][0], bg[NF][0], accG[(MH)*4+m_][NF], 0, 0, 0);                    \
    accU[(MH)*4+m_][NF] = __builtin_amdgcn_mfma_i32_16x16x64_i8(               \
        a[m_][0], bu[NF][0], accU[(MH)*4+m_][NF], 0, 0, 0);                    \
    accG[(MH)*4+m_][NF] = __builtin_amdgcn_mfma_i32_16x16x64_i8(               \
        a[m_][1], bg[NF][1], accG[(MH)*4+m_][NF], 0, 0, 0);                    \
    accU[(MH)*4+m_][NF] = __builtin_amdgcn_mfma_i32_16x16x64_i8(               \
        a[m_][1], bu[NF][1], accU[(MH)*4+m_][NF], 0, 0, 0);                    \
  } } while (0)

__global__ __launch_bounds__(512, 2)
void fc1_kernel(const int8_t* __restrict__ qx,
                const float* __restrict__ sx,
                const int8_t* __restrict__ gw,
                const int8_t* __restrict__ uw,
                const float* __restrict__ gws,
                const float* __restrict__ uws,
                const float* __restrict__ dis,
                int8_t* __restrict__ qh) {
    __shared__ __align__(16) int8_t lds[2][65536];   // per buf: A 32K | B 32K

    const int tid  = threadIdx.x;
    const int wave = tid >> 6;
    const int lane = tid & 63;
    const int wr = wave >> 2;          // 0..1  -> 128-row half
    const int wc = wave & 3;           // 0..3  -> 32 I-cols
    const int fr = lane & 15;
    const int fq = lane >> 4;

    // XCD swizzle: 1184 blocks = 8 XCD chunks of 148, m (8) fastest in chunk
    const int bid = blockIdx.x;
    const int gid = (bid & 7) * 148 + (bid >> 3);
    const int m0 = (gid & 7) * 256;
    const int n0 = (gid >> 3) * 128;

    const int rowS  = tid >> 3;                          // 0..63
    const int kOffS = ((tid & 7) ^ (rowS & 7)) * 16;     // pre-swizzled src
    const int8_t* gA = qx + (size_t)(m0 + rowS) * H_DIM + kOffS;
    const int8_t* gG = gw + (size_t)(n0 + rowS) * H_DIM + kOffS;
    const int8_t* gU = uw + (size_t)(n0 + rowS) * H_DIM + kOffS;

    const int sw0 = (fq ^ (fr & 7)) * 16;
    const int sw1 = ((4 + fq) ^ (fr & 7)) * 16;
    const int aOff = (wr * 128 + fr) * 128;
    const int bOff = (wc * 32 + fr) * 128;

    v4i accG[8][2] = {};
    v4i accU[8][2] = {};
    v4i a[4][2], bg[2][2], bu[2][2];

    {   // prologue: stage K-tile 0 into buf 0
        int8_t* lA = &lds[0][tid * 16];
        int8_t* lB = &lds[0][32768 + tid * 16];
#pragma unroll
        for (int j = 0; j < 4; ++j)
            async_copy16(gA + (size_t)(64 * j) * H_DIM, lA + j * 8192);
        async_copy16(gG,                         lB);
        async_copy16(gG + (size_t)64 * H_DIM,    lB + 8192);
        async_copy16(gU,                         lB + 16384);
        async_copy16(gU + (size_t)64 * H_DIM,    lB + 24576);
    }
    __syncthreads();

    for (int kt = 0; kt < H_DIM / 128; ++kt) {
        const int8_t* Ab = lds[kt & 1];
        const int8_t* Bb = Ab + 32768;
        int8_t* An = (int8_t*)lds[(kt & 1) ^ 1];
        int8_t* Bn = An + 32768;
        const bool pf = (kt + 1) < (H_DIM / 128);
        const int  kN = (kt + 1) * 128;

        // ---- phase 0: stage next-A, read A(mh=0)+B(nh=0), 16 MFMA
        if (pf) {
            int8_t* lA = An + tid * 16;
#pragma unroll
            for (int j = 0; j < 4; ++j)
                async_copy16(gA + kN + (size_t)(64 * j) * H_DIM, lA + j * 8192);
        }
        FC1_LOADA(0);
        FC1_LOADB(0);
        __builtin_amdgcn_s_barrier();
        __builtin_amdgcn_s_setprio(1);
        FC1_MFMA(0, 0);
        __builtin_amdgcn_s_setprio(0);
        __builtin_amdgcn_s_barrier();

        // ---- phase 1: stage next-B, read B(nh=1), 16 MFMA
        if (pf) {
            int8_t* lB = Bn + tid * 16;
            async_copy16(gG + kN,                      lB);
            async_copy16(gG + kN + (size_t)64 * H_DIM, lB + 8192);
            async_copy16(gU + kN,                      lB + 16384);
            async_copy16(gU + kN + (size_t)64 * H_DIM, lB + 24576);
        }
        FC1_LOADB(1);
        __builtin_amdgcn_s_barrier();
        __builtin_amdgcn_s_setprio(1);
        FC1_MFMA(0, 1);
        __builtin_amdgcn_s_setprio(0);
        __builtin_amdgcn_s_barrier();

        // ---- phase 2: read A(mh=1), 16 MFMA
        FC1_LOADA(1);
        __builtin_amdgcn_s_barrier();
        __builtin_amdgcn_s_setprio(1);
        FC1_MFMA(1, 0);
        __builtin_amdgcn_s_setprio(0);
        __builtin_amdgcn_s_barrier();

        // ---- phase 3: B frags already in regs, 16 MFMA; tile-end fence
        __builtin_amdgcn_s_setprio(1);
        FC1_MFMA(1, 1);
        __builtin_amdgcn_s_setprio(0);
        __syncthreads();   // drains vmcnt (staging issued 2.5 phases ago)
    }

    const float gscale = *gws;
    const float uscale = *uws;
    const float dis_v  = *dis;

    // C/D layout: row = (lane>>4)*4 + r, col = lane&15
#pragma unroll
    for (int M = 0; M < 8; ++M) {
#pragma unroll
        for (int r = 0; r < 4; ++r) {
            const int row = m0 + wr * 128 + M * 16 + fq * 4 + r;
            const float s  = sx[row];
            const float gs = s * gscale;
            const float us = s * uscale;
            const size_t base = (size_t)row * I_DIM + n0 + wc * 32;
#pragma unroll
            for (int nf = 0; nf < 2; ++nf) {
                float g = (float)accG[M][nf][r] * gs;
                float u = (float)accU[M][nf][r] * us;
                float h = (g / (1.0f + expf(-g))) * u;   // silu(g) * u
                float q = rintf(h / dis_v);
                q = fminf(fmaxf(q, -127.0f), 127.0f);
                qh[base + nf * 16 + fr] = (int8_t)q;
            }
        }
    }
}

// ---------------------------------------------------------------------------
// Kernel 3: fc2 — qh [T, I] x down_w [H, I] -> out [T, H] fp32
//   BM=128, BN=128, BK=128, 256 threads / 4 waves, wave tile 64x64.
//   2-phase per K-tile, double-buffered 64 KiB LDS (2 blocks/CU), prefetch
//   issued phase 0, drained at tile-end __syncthreads.
// ---------------------------------------------------------------------------
#define FC2_LOADA() do { _Pragma("unroll")                                     \
  for (int m_ = 0; m_ < 4; ++m_) {                                             \
    a[m_][0] = *(const v4i*)(Ab + aOff + m_*2048 + sw0);                       \
    a[m_][1] = *(const v4i*)(Ab + aOff + m_*2048 + sw1);                       \
  } } while (0)

#define FC2_LOADB(NH) do { _Pragma("unroll")                                   \
  for (int n_ = 0; n_ < 2; ++n_) {                                             \
    b[n_][0] = *(const v4i*)(Bb + bOff + ((NH)*2+n_)*2048 + sw0);              \
    b[n_][1] = *(const v4i*)(Bb + bOff + ((NH)*2+n_)*2048 + sw1);              \
  } } while (0)

#define FC2_MFMA(NH) do { _Pragma("unroll")                                    \
  for (int m_ = 0; m_ < 4; ++m_) { _Pragma("unroll")                           \
    for (int n_ = 0; n_ < 2; ++n_) {                                           \
      acc[m_][(NH)*2+n_] = __builtin_amdgcn_mfma_i32_16x16x64_i8(              \
          a[m_][0], b[n_][0], acc[m_][(NH)*2+n_], 0, 0, 0);                    \
      acc[m_][(NH)*2+n_] = __builtin_amdgcn_mfma_i32_16x16x64_i8(              \
          a[m_][1], b[n_][1], acc[m_][(NH)*2+n_], 0, 0, 0);                    \
    } } } while (0)

__global__ __launch_bounds__(256, 2)
void fc2_kernel(const int8_t* __restrict__ qh,
                const int8_t* __restrict__ dw,
                const float* __restrict__ dws,
                const float* __restrict__ dis,
                float* __restrict__ out) {
    __shared__ __align__(16) int8_t lds[2][32768];   // per buf: A 16K | B 16K

    const int tid  = threadIdx.x;
    const int wave = tid >> 6;
    const int lane = tid & 63;
    const int wr = wave >> 1;          // 0..1
    const int wc = wave & 1;           // 0..1
    const int fr = lane & 15;
    const int fq = lane >> 4;

    // XCD swizzle: 448 blocks = 8 chunks of 56, m (16) fastest in chunk
    const int bid = blockIdx.x;
    const int gid = (bid & 7) * 56 + (bid >> 3);
    const int m0 = (gid & 15) * 128;
    const int n0 = (gid >> 4) * 128;

    const int rowS  = tid >> 3;                          // 0..31
    const int kOffS = ((tid & 7) ^ (rowS & 7)) * 16;
    const int8_t* gA = qh + (size_t)(m0 + rowS) * I_DIM + kOffS;
    const int8_t* gW = dw + (size_t)(n0 + rowS) * I_DIM + kOffS;

    const int sw0 = (fq ^ (fr & 7)) * 16;
    const int sw1 = ((4 + fq) ^ (fr & 7)) * 16;
    const int aOff = (wr * 64 + fr) * 128;
    const int bOff = (wc * 64 + fr) * 128;

    v4i acc[4][4] = {};
    v4i a[4][2], b[2][2];

    {   // prologue: stage K-tile 0
        int8_t* lA = &lds[0][tid * 16];
        int8_t* lB = &lds[0][16384 + tid * 16];
#pragma unroll
        for (int j = 0; j < 4; ++j) {
            async_copy16(gA + (size_t)(32 * j) * I_DIM, lA + j * 4096);
            async_copy16(gW + (size_t)(32 * j) * I_DIM, lB + j * 4096);
        }
    }
    __syncthreads();

    for (int kt = 0; kt < I_DIM / 128; ++kt) {
        const int8_t* Ab = lds[kt & 1];
        const int8_t* Bb = Ab + 16384;
        int8_t* An = (int8_t*)lds[(kt & 1) ^ 1];
        int8_t* Bn = An + 16384;
        const bool pf = (kt + 1) < (I_DIM / 128);
        const int  kN = (kt + 1) * 128;

        // ---- phase 0: stage next tile, read A + B(nh=0), 16 MFMA
        if (pf) {
            int8_t* lA = An + tid * 16;
            int8_t* lB = Bn + tid * 16;
#pragma unroll
            for (int j = 0; j < 4; ++j) {
                async_copy16(gA + kN + (size_t)(32 * j) * I_DIM, lA + j * 4096);
                async_copy16(gW + kN + (size_t)(32 * j) * I_DIM, lB + j * 4096);
            }
        }
        FC2_LOADA();
        FC2_LOADB(0);
        __builtin_amdgcn_s_barrier();
        __builtin_amdgcn_s_setprio(1);
        FC2_MFMA(0);
        __builtin_amdgcn_s_setprio(0);
        __builtin_amdgcn_s_barrier();

        // ---- phase 1: read B(nh=1), 16 MFMA; tile-end fence
        FC2_LOADB(1);
        __builtin_amdgcn_s_barrier();
        __builtin_amdgcn_s_setprio(1);
        FC2_MFMA(1);
        __builtin_amdgcn_s_setprio(0);
        __syncthreads();
    }

    const float sc = (*dis) * (*dws);
#pragma unroll
    for (int m_ = 0; m_ < 4; ++m_)
#pragma unroll
        for (int n_ = 0; n_ < 4; ++n_)
#pragma unroll
            for (int r = 0; r < 4; ++r) {
                const int row = m0 + wr * 64 + m_ * 16 + fq * 4 + r;
                const int col = n0 + wc * 64 + n_ * 16 + fr;
                out[(size_t)row * H_DIM + col] = (float)acc[m_][n_][r] * sc;
            }
}

// ---------------------------------------------------------------------------
extern "C" void kernel_launch(void* const* d_in, const int* in_sizes, int n_in,
                              void* d_out, int out_size, void* d_ws, size_t ws_size,
                              hipStream_t stream) {
    const float* x    = (const float*)d_in[0];
    const int*   gw32 = (const int*)d_in[1];   // integer inputs arrive as int32
    const int*   uw32 = (const int*)d_in[2];
    const int*   dw32 = (const int*)d_in[3];
    const float* gws  = (const float*)d_in[4];
    const float* uws  = (const float*)d_in[5];
    const float* dws  = (const float*)d_in[6];
    const float* dis  = (const float*)d_in[7];
    float* out = (float*)d_out;

    // workspace: qx [T*H] i8 | sx [T] f32 | qh [T*I] i8 | gw8 | uw8 | dw8
    const size_t W = (size_t)I_DIM * H_DIM;
    int8_t* qx  = (int8_t*)d_ws;
    float*  sx  = (float*)((char*)d_ws + (size_t)TOKENS * H_DIM);
    int8_t* qh  = (int8_t*)((char*)d_ws + (size_t)TOKENS * H_DIM + TOKENS * 4);
    int8_t* gw8 = (int8_t*)((char*)d_ws + (size_t)TOKENS * H_DIM + TOKENS * 4
                            + (size_t)TOKENS * I_DIM);
    int8_t* uw8 = gw8 + W;
    int8_t* dw8 = uw8 + W;

    const int pb = (int)(W / 4 / 256);   // 66304 blocks per matrix, exact
    pack3_kernel<<<3 * pb, 256, 0, stream>>>(gw32, gw8, uw32, uw8, dw32, dw8, pb);

    quant_x_kernel<<<TOKENS, 256, 0, stream>>>(x, qx, sx);

    fc1_kernel<<<(TOKENS / 256) * (I_DIM / 128), 512, 0, stream>>>(
        qx, sx, gw8, uw8, gws, uws, dis, qh);

    fc2_kernel<<<(TOKENS / 128) * (H_DIM / 128), 256, 0, stream>>>(
        qh, dw8, dws, dis, out);
}